// Round 12
// baseline (166.320 us; speedup 1.0000x reference)
//
#include <hip/hip_runtime.h>

// FNO spectral convolution, truncated separable DFT formulation.
// B=8, H=W=256, C_IN=C_OUT=64, modes 32 x 17 (rows fftshift-centered: k_m = m-16).
//
// Round-12: revert radix-4 (r11 regression: 2 waves/SIMD occupancy + strided
// streams -> latency-exposed). Config = round-10 measured-best (~107us implied):
// Goertzel k1 + 512-thr k2b + LDS-table k3 -- with ONE change: k3 processes
// 4 rows/block so each 34-float LDS twiddle row feeds 136 FMAs (r10 PMC:
// k3 was LDS-broadcast-issue-bound, 9 ds_read_b128/iter ~= 46us/CU; halved).
//
// ws layout (floats):
//   twA [256 w][18 pairs]  : 9216   (cos,sin of +2pi n w/256; pair 17 = pad)
//   twB [256 h][32 m][2]   : 16384
//   twC [32]               : 32     (2*cos(2pi n/256), n<17)
//   G   [B][H][17][64][2]  : 4456448   (aliased by Z after k2a)
//   T   [B][H][17][64][2]  : 4456448   (aliased by P before k2c)
//   P [4 hq][136 bn][32 m][64 i][2] -> lives in T's slot
//   Z [8 b][17 n][32 m][64 o][2]    -> lives in dead G's slot

#define NB 8
#define NH 256
#define NW 256
#define NC 64
#define NM1 32
#define NM2 17
#define HQ 4

__global__ void k0_tw(float* __restrict__ twA, float* __restrict__ twB,
                      float* __restrict__ twC) {
    const float STEP = 0.02454369260617026f; // 2*pi/256
    int t = blockIdx.x * 256 + threadIdx.x;
    if (t < 256 * 18) {
        int w = t / 18, nn = t % 18;
        if (nn < 17) {
            int ph = (nn * w) & 255;
            float ang = (float)ph * STEP;
            twA[w * 36 + 2 * nn + 0] = cosf(ang);
            twA[w * 36 + 2 * nn + 1] = sinf(ang);
        } else {
            twA[w * 36 + 34] = 0.f;
            twA[w * 36 + 35] = 0.f;
        }
    }
    if (t < 256 * 32) {
        int h = t >> 5, m = t & 31;
        int ph = ((m - 16) * h) & 255; // two's complement & 255 == mod 256
        float ang = (float)ph * STEP;
        twB[t * 2 + 0] = cosf(ang);
        twB[t * 2 + 1] = sinf(ang);
    }
    if (t < 17) {
        twC[t] = 2.0f * cosf((float)t * STEP);
    }
}

// K1 (real Goertzel, round-9/10 verbatim): G[n][i] = sum_w x[bh,w,i] cis(-2pi n w/256).
// s_j = x_j + 2c_n s_{j-1} - s_{j-2}; fixup Q=(c s63 - s62)+i(sn s63);
// rotate (-i)^{n(wq+1)}; 4-way LDS reduce. 2 rows/block, grid 1024.
__global__ __launch_bounds__(256) void k1_fwdW(const float* __restrict__ x,
                                               const float* __restrict__ twA,
                                               const float* __restrict__ twC,
                                               float* __restrict__ G) {
    __shared__ float lre[4][17][64];
    __shared__ float lim[4][17][64];
    const int tid = threadIdx.x;
    const int i = tid & 63;
    const int wq_u = __builtin_amdgcn_readfirstlane(tid >> 6);
    const int bh0 = blockIdx.x * 2;

    float twoc[17], cn[17], sn[17];
    #pragma unroll
    for (int n = 0; n < 17; ++n) {
        twoc[n] = twC[n];
        cn[n] = twA[36 + 2 * n];
        sn[n] = twA[36 + 2 * n + 1];
    }

    float s1a[17], s2a[17], s1b[17], s2b[17];
    #pragma unroll
    for (int n = 0; n < 17; ++n) { s1a[n]=0.f; s2a[n]=0.f; s1b[n]=0.f; s2b[n]=0.f; }

    const float* xb0 = x + (size_t)bh0 * (NW * NC) + (size_t)wq_u * 64 * 64 + i;
    const float* xb1 = xb0 + NW * NC;
    #pragma unroll 2
    for (int j = 0; j < 64; j += 2) {
        float x0a = xb0[(size_t)j * 64];
        float x0b = xb0[(size_t)(j + 1) * 64];
        float x1a = xb1[(size_t)j * 64];
        float x1b = xb1[(size_t)(j + 1) * 64];
        #pragma unroll
        for (int n = 0; n < 17; ++n) {
            float ta = fmaf(twoc[n], s1a[n], x0a) - s2a[n];
            float tb = fmaf(twoc[n], ta, x0b) - s1a[n];
            s2a[n] = ta; s1a[n] = tb;
            float ua = fmaf(twoc[n], s1b[n], x1a) - s2b[n];
            float ub = fmaf(twoc[n], ua, x1b) - s1b[n];
            s2b[n] = ua; s1b[n] = ub;
        }
    }

    #pragma unroll
    for (int n = 0; n < 17; ++n) {
        float qr0 = fmaf(cn[n], s1a[n], -s2a[n]);
        float qi0 = sn[n] * s1a[n];
        float qr1 = fmaf(cn[n], s1b[n], -s2b[n]);
        float qi1 = sn[n] * s1b[n];
        int k = (n * (wq_u + 1)) & 3;
        float r0r = (k==0)? qr0 : (k==1)? qi0 : (k==2)? -qr0 : -qi0;
        float r0i = (k==0)? qi0 : (k==1)? -qr0 : (k==2)? -qi0 : qr0;
        float r1r = (k==0)? qr1 : (k==1)? qi1 : (k==2)? -qr1 : -qi1;
        float r1i = (k==0)? qi1 : (k==1)? -qr1 : (k==2)? -qi1 : qr1;
        s1a[n] = r0r; s2a[n] = r0i;
        s1b[n] = r1r; s2b[n] = r1i;
    }

    #pragma unroll
    for (int n = 0; n < 17; ++n) { lre[wq_u][n][i] = s1a[n]; lim[wq_u][n][i] = s2a[n]; }
    __syncthreads();
    float2* G0 = (float2*)G + (size_t)bh0 * 17 * 64;
    for (int n = wq_u; n < 17; n += 4) {
        float re = (lre[0][n][i] + lre[1][n][i]) + (lre[2][n][i] + lre[3][n][i]);
        float im = (lim[0][n][i] + lim[1][n][i]) + (lim[2][n][i] + lim[3][n][i]);
        G0[n * 64 + i] = make_float2(re, im);
    }
    __syncthreads();
    #pragma unroll
    for (int n = 0; n < 17; ++n) { lre[wq_u][n][i] = s1b[n]; lim[wq_u][n][i] = s2b[n]; }
    __syncthreads();
    float2* G1 = G0 + 17 * 64;
    for (int n = wq_u; n < 17; n += 4) {
        float re = (lre[0][n][i] + lre[1][n][i]) + (lre[2][n][i] + lre[3][n][i]);
        float im = (lim[0][n][i] + lim[1][n][i]) + (lim[2][n][i] + lim[3][n][i]);
        G1[n * 64 + i] = make_float2(re, im);
    }
}

// K2a: partial H-DFT. grid (136 bn, 4 hq). (unchanged)
__global__ __launch_bounds__(256) void k2a_hdft(const float* __restrict__ G,
                                                const float* __restrict__ twB,
                                                float* __restrict__ P) {
    const int bn = blockIdx.x;
    const int b = bn / 17, n = bn % 17;
    const int hq = blockIdx.y;
    const int t = threadIdx.x;
    const int lane = t & 63;
    const int q_u = __builtin_amdgcn_readfirstlane(t >> 6);

    float ar[8], ai[8];
    #pragma unroll
    for (int j = 0; j < 8; ++j) { ar[j] = 0.f; ai[j] = 0.f; }

    const float2* Gb = (const float2*)G + ((size_t)b * 256 * 17 + n) * 64 + lane;
    #pragma unroll 2
    for (int hh = 0; hh < 64; ++hh) {
        int h = hq * 64 + hh;
        float2 g = Gb[(size_t)h * (17 * 64)];
        const float* tw = twB + (h * 32 + q_u * 8) * 2;
        #pragma unroll
        for (int j = 0; j < 8; ++j) {
            float c = tw[2 * j], s = tw[2 * j + 1];
            ar[j] = fmaf(g.x, c, fmaf(g.y, s, ar[j]));
            ai[j] = fmaf(g.y, c, fmaf(-g.x, s, ai[j]));
        }
    }
    float2* Pp = (float2*)P + (((size_t)hq * 136 + bn) * 32 + q_u * 8) * 64 + lane;
    #pragma unroll
    for (int j = 0; j < 8; ++j) Pp[j * 64] = make_float2(ar[j], ai[j]);
}

// K2b: 512 threads, wave-per-b. (round-10 version -- measured ~38us saving)
__global__ __launch_bounds__(512) void k2b_mix(const float* __restrict__ P,
                                               const float* __restrict__ Wr,
                                               const float* __restrict__ Wi,
                                               float* __restrict__ Z) {
    __shared__ float2 xs[8 * 64]; // [b][i]
    const int mn = blockIdx.x;
    const int m = mn & 31, n = mn >> 5;
    const int t = threadIdx.x;
    const int lane = t & 63;
    const int q_u = __builtin_amdgcn_readfirstlane(t >> 6); // b for this wave

    {
        int b = t >> 6, i = t & 63;
        const float2* Pp = (const float2*)P + (((size_t)(b * 17 + n)) * 32 + m) * 64 + i;
        float re = 0.f, im = 0.f;
        #pragma unroll
        for (int hq = 0; hq < HQ; ++hq) {
            float2 pv = Pp[(size_t)hq * (136 * 32 * 64)];
            re += pv.x; im += pv.y;
        }
        xs[t] = make_float2(re, im);
    }
    __syncthreads();

    const float scale = (n == 0 ? 1.0f : 2.0f) * (1.0f / 65536.0f);
    float zr = 0.f, zi = 0.f;
    const float* Wrp = Wr + (((size_t)m * 17 + n) * 64) * 64 + lane;
    const float* Wip = Wi + (((size_t)m * 17 + n) * 64) * 64 + lane;
    #pragma unroll 4
    for (int i = 0; i < 64; ++i) {
        float wr = Wrp[(size_t)i * 64], wi = Wip[(size_t)i * 64];
        float2 xv = xs[q_u * 64 + i];  // wave-uniform -> LDS broadcast
        zr = fmaf(xv.x, wr, fmaf(-xv.y, wi, zr));
        zi = fmaf(xv.x, wi, fmaf(xv.y, wr, zi));
    }
    float2* Zp = (float2*)Z;
    Zp[(((size_t)q_u * 17 + n) * 32 + m) * 64 + lane] = make_float2(zr * scale, zi * scale);
}

// K2c: inverse H-DFT. (unchanged)
__global__ __launch_bounds__(256) void k2c_ihdft(const float* __restrict__ Z,
                                                 const float* __restrict__ twB,
                                                 float* __restrict__ T) {
    __shared__ float2 zs[32 * 64];
    const int bn = blockIdx.x;
    const int b = bn / 17, n = bn % 17;
    const int hq = blockIdx.y;
    const int t = threadIdx.x;
    const int lane = t & 63;
    const int q_u = __builtin_amdgcn_readfirstlane(t >> 6);

    const float2* Zp = (const float2*)Z + (((size_t)b * 17 + n) * 32) * 64;
    #pragma unroll
    for (int r = 0; r < 8; ++r) zs[r * 256 + t] = Zp[r * 256 + t];
    __syncthreads();

    float2* Tb = (float2*)T + ((size_t)b * 256 * 17 + n) * 64 + lane;
    #pragma unroll 2
    for (int jj = 0; jj < 8; ++jj) {
        int h = hq * 32 + q_u * 8 + jj;
        const float* tw = twB + h * 64;
        float re0 = 0, im0 = 0, re1 = 0, im1 = 0;
        #pragma unroll
        for (int m = 0; m < 32; m += 2) {
            float2 z0 = zs[m * 64 + lane];
            float c0 = tw[2 * m + 0], s0 = tw[2 * m + 1];
            re0 = fmaf(z0.x, c0, fmaf(-z0.y, s0, re0));
            im0 = fmaf(z0.x, s0, fmaf(z0.y, c0, im0));
            float2 z1 = zs[(m + 1) * 64 + lane];
            float c1 = tw[2 * m + 2], s1 = tw[2 * m + 3];
            re1 = fmaf(z1.x, c1, fmaf(-z1.y, s1, re1));
            im1 = fmaf(z1.x, s1, fmaf(z1.y, c1, im1));
        }
        Tb[(size_t)h * (17 * 64)] = make_float2(re0 + re1, im0 + im1);
    }
}

// K3 (LDS twiddle table, 4 rows/block): y[bh,w,o] = sum_n tr_n c[w,n] - ti_n s[w,n].
// Table [256][36] staged once (36.9KB). Each 34-float row read feeds 136 FMAs
// (4 rows) -- halves the LDS-broadcast issue cost per row vs the 2-row r10
// version (r10 PMC: that was the binding pipe). Grid 512.
__global__ __launch_bounds__(256) void k3_invW(const float* __restrict__ T,
                                               const float* __restrict__ twA,
                                               float* __restrict__ y) {
    __shared__ float tws[256 * 36]; // 36.9 KB
    const int tid = threadIdx.x;
    const int o = tid & 63;
    const int wq_u = __builtin_amdgcn_readfirstlane(tid >> 6);
    const int bh0 = blockIdx.x * 4;

    {
        const float4* src = (const float4*)twA;
        float4* dst = (float4*)tws;
        #pragma unroll
        for (int r = 0; r < 9; ++r) dst[r * 256 + tid] = src[r * 256 + tid];
    }

    const float2* Tb = (const float2*)T + (size_t)bh0 * 17 * 64;
    float tr[4][17], ti[4][17];
    #pragma unroll
    for (int r = 0; r < 4; ++r) {
        #pragma unroll
        for (int n = 0; n < 17; ++n) {
            float2 v = Tb[(r * 17 + n) * 64 + o];
            tr[r][n] = v.x; ti[r][n] = v.y;
        }
    }
    __syncthreads();

    float* yb = y + (size_t)bh0 * (NW * NC) + o;
    #pragma unroll 1
    for (int ww = 0; ww < 64; ++ww) {
        int w = wq_u * 64 + ww;
        const float* tw = &tws[w * 36];     // wave-uniform LDS reads, once per 136 FMA
        float a0 = 0.f, a1 = 0.f, a2 = 0.f, a3 = 0.f;
        #pragma unroll
        for (int n = 0; n < 17; ++n) {
            float c = tw[2 * n], s = tw[2 * n + 1];
            a0 = fmaf(tr[0][n], c, fmaf(-ti[0][n], s, a0));
            a1 = fmaf(tr[1][n], c, fmaf(-ti[1][n], s, a1));
            a2 = fmaf(tr[2][n], c, fmaf(-ti[2][n], s, a2));
            a3 = fmaf(tr[3][n], c, fmaf(-ti[3][n], s, a3));
        }
        yb[(size_t)w * 64]                    = a0;  // coalesced 256B/wave each
        yb[(size_t)(NW * NC) + (size_t)w * 64]     = a1;
        yb[(size_t)(2 * NW * NC) + (size_t)w * 64] = a2;
        yb[(size_t)(3 * NW * NC) + (size_t)w * 64] = a3;
    }
}

extern "C" void kernel_launch(void* const* d_in, const int* in_sizes, int n_in,
                              void* d_out, int out_size, void* d_ws, size_t ws_size,
                              hipStream_t stream) {
    (void)in_sizes; (void)n_in; (void)out_size; (void)ws_size;
    const float* x  = (const float*)d_in[0];
    const float* Wr = (const float*)d_in[1];
    const float* Wi = (const float*)d_in[2];
    float* out = (float*)d_out;
    float* ws  = (float*)d_ws;

    float* twA = ws;                 // 9216 floats (padded [256][36])
    float* twB = ws + 9216;          // 16384 floats
    float* twC = ws + 25600;         // 32 floats
    float* G   = ws + 25632;         // 4456448 floats
    float* T   = G + 4456448;        // 4456448 floats
    float* P   = T;                  // alias: partials live in T's slot
    float* Z   = G;                  // alias: Z lives in dead G's slot

    k0_tw<<<32, 256, 0, stream>>>(twA, twB, twC);
    k1_fwdW<<<NB * NH / 2, 256, 0, stream>>>(x, twA, twC, G);
    k2a_hdft<<<dim3(NB * NM2, HQ), 256, 0, stream>>>(G, twB, P);
    k2b_mix<<<NM1 * NM2, 512, 0, stream>>>(P, Wr, Wi, Z);
    k2c_ihdft<<<dim3(NB * NM2, 8), 256, 0, stream>>>(Z, twB, T);
    k3_invW<<<NB * NH / 4, 256, 0, stream>>>(T, twA, out);
}

// Round 13
// 134.313 us; speedup vs baseline: 1.2383x; 1.2383x over previous
//
#include <hip/hip_runtime.h>

// FNO spectral convolution, truncated separable DFT formulation.
// B=8, H=W=256, C_IN=C_OUT=64, modes 32 x 17 (rows fftshift-centered: k_m = m-16).
//
// Round-13: k3 = radix-4 MATH (r11, verified) + LDS-broadcast DELIVERY (r10,
// measured-healthy) + 1024-block grid. Per w'-iter: 9 broadcast ds_read_b128
// feed 2 rows x 4 outputs (116 VALU) -> LDS reads/block 576->144 (r10 PMC:
// LDS pipe was k3's limiter at ~46us), VALU halved, y-store stream (134MB,
// ~21us) becomes the floor. All grid/occupancy parameters unchanged from the
// measured-best r10 config (r5/r11/r12 lesson: never trade grid-parallelism
// for per-wave amortization).
//
// ws layout (floats):
//   twD [64 w'][18 pairs]  : 2304   (cos,sin of +2pi n w'/256; pair 17 = pad)
//   twB [256 h][32 m][2]   : 16384
//   twC [32]               : 32     (2*cos(2pi n/256), n<17)
//   G   [B][H][17][64][2]  : 4456448   (aliased by Z after k2a)
//   T   [B][H][17][64][2]  : 4456448   (aliased by P before k2c)
//   P [4 hq][136 bn][32 m][64 i][2] -> lives in T's slot
//   Z [8 b][17 n][32 m][64 o][2]    -> lives in dead G's slot

#define NB 8
#define NH 256
#define NW 256
#define NC 64
#define NM1 32
#define NM2 17
#define HQ 4

__global__ void k0_tw(float* __restrict__ twD, float* __restrict__ twB,
                      float* __restrict__ twC) {
    const float STEP = 0.02454369260617026f; // 2*pi/256
    int t = blockIdx.x * 256 + threadIdx.x;
    if (t < 64 * 18) {
        int w = t / 18, nn = t % 18;
        if (nn < 17) {
            int ph = (nn * w) & 255;
            float ang = (float)ph * STEP;
            twD[w * 36 + 2 * nn + 0] = cosf(ang);
            twD[w * 36 + 2 * nn + 1] = sinf(ang);
        } else {
            twD[w * 36 + 34] = 0.f;
            twD[w * 36 + 35] = 0.f;
        }
    }
    if (t < 256 * 32) {
        int h = t >> 5, m = t & 31;
        int ph = ((m - 16) * h) & 255; // two's complement & 255 == mod 256
        float ang = (float)ph * STEP;
        twB[t * 2 + 0] = cosf(ang);
        twB[t * 2 + 1] = sinf(ang);
    }
    if (t < 17) {
        twC[t] = 2.0f * cosf((float)t * STEP);
    }
}

// K1 (real Goertzel, r9/r10 verbatim; constants now from twD row w'=1):
// G[n][i] = sum_w x[bh,w,i] cis(-2pi n w/256). s_j = x_j + 2c_n s_{j-1} - s_{j-2};
// fixup Q=(c s63 - s62)+i(sn s63); rotate (-i)^{n(wq+1)}; 4-way LDS reduce.
// 2 rows/block, grid 1024.
__global__ __launch_bounds__(256) void k1_fwdW(const float* __restrict__ x,
                                               const float* __restrict__ twD,
                                               const float* __restrict__ twC,
                                               float* __restrict__ G) {
    __shared__ float lre[4][17][64];
    __shared__ float lim[4][17][64];
    const int tid = threadIdx.x;
    const int i = tid & 63;
    const int wq_u = __builtin_amdgcn_readfirstlane(tid >> 6);
    const int bh0 = blockIdx.x * 2;

    float twoc[17], cn[17], sn[17];
    #pragma unroll
    for (int n = 0; n < 17; ++n) {
        twoc[n] = twC[n];
        cn[n] = twD[36 + 2 * n];      // row w'=1: cis(2pi n/256)
        sn[n] = twD[36 + 2 * n + 1];
    }

    float s1a[17], s2a[17], s1b[17], s2b[17];
    #pragma unroll
    for (int n = 0; n < 17; ++n) { s1a[n]=0.f; s2a[n]=0.f; s1b[n]=0.f; s2b[n]=0.f; }

    const float* xb0 = x + (size_t)bh0 * (NW * NC) + (size_t)wq_u * 64 * 64 + i;
    const float* xb1 = xb0 + NW * NC;
    #pragma unroll 2
    for (int j = 0; j < 64; j += 2) {
        float x0a = xb0[(size_t)j * 64];
        float x0b = xb0[(size_t)(j + 1) * 64];
        float x1a = xb1[(size_t)j * 64];
        float x1b = xb1[(size_t)(j + 1) * 64];
        #pragma unroll
        for (int n = 0; n < 17; ++n) {
            float ta = fmaf(twoc[n], s1a[n], x0a) - s2a[n];
            float tb = fmaf(twoc[n], ta, x0b) - s1a[n];
            s2a[n] = ta; s1a[n] = tb;
            float ua = fmaf(twoc[n], s1b[n], x1a) - s2b[n];
            float ub = fmaf(twoc[n], ua, x1b) - s1b[n];
            s2b[n] = ua; s1b[n] = ub;
        }
    }

    #pragma unroll
    for (int n = 0; n < 17; ++n) {
        float qr0 = fmaf(cn[n], s1a[n], -s2a[n]);
        float qi0 = sn[n] * s1a[n];
        float qr1 = fmaf(cn[n], s1b[n], -s2b[n]);
        float qi1 = sn[n] * s1b[n];
        int k = (n * (wq_u + 1)) & 3;
        float r0r = (k==0)? qr0 : (k==1)? qi0 : (k==2)? -qr0 : -qi0;
        float r0i = (k==0)? qi0 : (k==1)? -qr0 : (k==2)? -qi0 : qr0;
        float r1r = (k==0)? qr1 : (k==1)? qi1 : (k==2)? -qr1 : -qi1;
        float r1i = (k==0)? qi1 : (k==1)? -qr1 : (k==2)? -qi1 : qr1;
        s1a[n] = r0r; s2a[n] = r0i;
        s1b[n] = r1r; s2b[n] = r1i;
    }

    #pragma unroll
    for (int n = 0; n < 17; ++n) { lre[wq_u][n][i] = s1a[n]; lim[wq_u][n][i] = s2a[n]; }
    __syncthreads();
    float2* G0 = (float2*)G + (size_t)bh0 * 17 * 64;
    for (int n = wq_u; n < 17; n += 4) {
        float re = (lre[0][n][i] + lre[1][n][i]) + (lre[2][n][i] + lre[3][n][i]);
        float im = (lim[0][n][i] + lim[1][n][i]) + (lim[2][n][i] + lim[3][n][i]);
        G0[n * 64 + i] = make_float2(re, im);
    }
    __syncthreads();
    #pragma unroll
    for (int n = 0; n < 17; ++n) { lre[wq_u][n][i] = s1b[n]; lim[wq_u][n][i] = s2b[n]; }
    __syncthreads();
    float2* G1 = G0 + 17 * 64;
    for (int n = wq_u; n < 17; n += 4) {
        float re = (lre[0][n][i] + lre[1][n][i]) + (lre[2][n][i] + lre[3][n][i]);
        float im = (lim[0][n][i] + lim[1][n][i]) + (lim[2][n][i] + lim[3][n][i]);
        G1[n * 64 + i] = make_float2(re, im);
    }
}

// K2a: partial H-DFT. grid (136 bn, 4 hq). (unchanged)
__global__ __launch_bounds__(256) void k2a_hdft(const float* __restrict__ G,
                                                const float* __restrict__ twB,
                                                float* __restrict__ P) {
    const int bn = blockIdx.x;
    const int b = bn / 17, n = bn % 17;
    const int hq = blockIdx.y;
    const int t = threadIdx.x;
    const int lane = t & 63;
    const int q_u = __builtin_amdgcn_readfirstlane(t >> 6);

    float ar[8], ai[8];
    #pragma unroll
    for (int j = 0; j < 8; ++j) { ar[j] = 0.f; ai[j] = 0.f; }

    const float2* Gb = (const float2*)G + ((size_t)b * 256 * 17 + n) * 64 + lane;
    #pragma unroll 2
    for (int hh = 0; hh < 64; ++hh) {
        int h = hq * 64 + hh;
        float2 g = Gb[(size_t)h * (17 * 64)];
        const float* tw = twB + (h * 32 + q_u * 8) * 2;
        #pragma unroll
        for (int j = 0; j < 8; ++j) {
            float c = tw[2 * j], s = tw[2 * j + 1];
            ar[j] = fmaf(g.x, c, fmaf(g.y, s, ar[j]));
            ai[j] = fmaf(g.y, c, fmaf(-g.x, s, ai[j]));
        }
    }
    float2* Pp = (float2*)P + (((size_t)hq * 136 + bn) * 32 + q_u * 8) * 64 + lane;
    #pragma unroll
    for (int j = 0; j < 8; ++j) Pp[j * 64] = make_float2(ar[j], ai[j]);
}

// K2b: 512 threads, wave-per-b. (r10 version -- measured ~38us saving)
__global__ __launch_bounds__(512) void k2b_mix(const float* __restrict__ P,
                                               const float* __restrict__ Wr,
                                               const float* __restrict__ Wi,
                                               float* __restrict__ Z) {
    __shared__ float2 xs[8 * 64]; // [b][i]
    const int mn = blockIdx.x;
    const int m = mn & 31, n = mn >> 5;
    const int t = threadIdx.x;
    const int lane = t & 63;
    const int q_u = __builtin_amdgcn_readfirstlane(t >> 6); // b for this wave

    {
        int b = t >> 6, i = t & 63;
        const float2* Pp = (const float2*)P + (((size_t)(b * 17 + n)) * 32 + m) * 64 + i;
        float re = 0.f, im = 0.f;
        #pragma unroll
        for (int hq = 0; hq < HQ; ++hq) {
            float2 pv = Pp[(size_t)hq * (136 * 32 * 64)];
            re += pv.x; im += pv.y;
        }
        xs[t] = make_float2(re, im);
    }
    __syncthreads();

    const float scale = (n == 0 ? 1.0f : 2.0f) * (1.0f / 65536.0f);
    float zr = 0.f, zi = 0.f;
    const float* Wrp = Wr + (((size_t)m * 17 + n) * 64) * 64 + lane;
    const float* Wip = Wi + (((size_t)m * 17 + n) * 64) * 64 + lane;
    #pragma unroll 4
    for (int i = 0; i < 64; ++i) {
        float wr = Wrp[(size_t)i * 64], wi = Wip[(size_t)i * 64];
        float2 xv = xs[q_u * 64 + i];  // wave-uniform -> LDS broadcast
        zr = fmaf(xv.x, wr, fmaf(-xv.y, wi, zr));
        zi = fmaf(xv.x, wi, fmaf(xv.y, wr, zi));
    }
    float2* Zp = (float2*)Z;
    Zp[(((size_t)q_u * 17 + n) * 32 + m) * 64 + lane] = make_float2(zr * scale, zi * scale);
}

// K2c: inverse H-DFT. (unchanged)
__global__ __launch_bounds__(256) void k2c_ihdft(const float* __restrict__ Z,
                                                 const float* __restrict__ twB,
                                                 float* __restrict__ T) {
    __shared__ float2 zs[32 * 64];
    const int bn = blockIdx.x;
    const int b = bn / 17, n = bn % 17;
    const int hq = blockIdx.y;
    const int t = threadIdx.x;
    const int lane = t & 63;
    const int q_u = __builtin_amdgcn_readfirstlane(t >> 6);

    const float2* Zp = (const float2*)Z + (((size_t)b * 17 + n) * 32) * 64;
    #pragma unroll
    for (int r = 0; r < 8; ++r) zs[r * 256 + t] = Zp[r * 256 + t];
    __syncthreads();

    float2* Tb = (float2*)T + ((size_t)b * 256 * 17 + n) * 64 + lane;
    #pragma unroll 2
    for (int jj = 0; jj < 8; ++jj) {
        int h = hq * 32 + q_u * 8 + jj;
        const float* tw = twB + h * 64;
        float re0 = 0, im0 = 0, re1 = 0, im1 = 0;
        #pragma unroll
        for (int m = 0; m < 32; m += 2) {
            float2 z0 = zs[m * 64 + lane];
            float c0 = tw[2 * m + 0], s0 = tw[2 * m + 1];
            re0 = fmaf(z0.x, c0, fmaf(-z0.y, s0, re0));
            im0 = fmaf(z0.x, s0, fmaf(z0.y, c0, im0));
            float2 z1 = zs[(m + 1) * 64 + lane];
            float c1 = tw[2 * m + 2], s1 = tw[2 * m + 3];
            re1 = fmaf(z1.x, c1, fmaf(-z1.y, s1, re1));
            im1 = fmaf(z1.x, s1, fmaf(z1.y, c1, im1));
        }
        Tb[(size_t)h * (17 * 64)] = make_float2(re0 + re1, im0 + im1);
    }
}

// K3 (radix-4 math + LDS-broadcast twiddles): y[bh, w'+64j, o] from class
// accumulators; y(w'+64j) = Re(sum_k i^{jk} (P_k + iQ_k)); Q0,Q2 unused.
// 2 rows/block, grid 1024 (r10 occupancy); wave q covers w' in [16q,16q+16).
// Per iter: 9 broadcast ds_read_b128 feed 100 FMA + 16 epi + 8 coalesced
// 256B stores. LDS table 9.2 KB staged once.
__global__ __launch_bounds__(256) void k3_invW(const float* __restrict__ T,
                                               const float* __restrict__ twD,
                                               float* __restrict__ y) {
    __shared__ float tws[64 * 36]; // 9.2 KB
    const int tid = threadIdx.x;
    const int o = tid & 63;
    const int q_u = __builtin_amdgcn_readfirstlane(tid >> 6);
    const int bh0 = blockIdx.x * 2;

    // stage table: 576 float4
    {
        const float4* src = (const float4*)twD;
        float4* dst = (float4*)tws;
        #pragma unroll
        for (int v = tid; v < 576; v += 256) dst[v] = src[v];
    }

    const float2* T0 = (const float2*)T + (size_t)bh0 * 17 * 64;
    const float2* T1 = T0 + 17 * 64;
    float tr0[17], ti0[17], tr1[17], ti1[17];
    #pragma unroll
    for (int n = 0; n < 17; ++n) {
        float2 v0 = T0[n * 64 + o];
        tr0[n] = v0.x; ti0[n] = v0.y;
        float2 v1 = T1[n * 64 + o];
        tr1[n] = v1.x; ti1[n] = v1.y;
    }
    __syncthreads();

    float* yb0 = y + (size_t)bh0 * (NW * NC) + o;
    float* yb1 = yb0 + NW * NC;
    #pragma unroll 2
    for (int it = 0; it < 16; ++it) {
        const int wp = q_u * 16 + it;
        const float* tw = &tws[wp * 36];        // wave-uniform -> broadcast
        float P0a=0.f,P1a=0.f,P2a=0.f,P3a=0.f,Q1a=0.f,Q3a=0.f;
        float P0b=0.f,P1b=0.f,P2b=0.f,P3b=0.f,Q1b=0.f,Q3b=0.f;
        #pragma unroll
        for (int n = 0; n < 17; n += 4) {       // k=0: P only
            float c = tw[2 * n], s = tw[2 * n + 1];
            P0a = fmaf(tr0[n], c, fmaf(-ti0[n], s, P0a));
            P0b = fmaf(tr1[n], c, fmaf(-ti1[n], s, P0b));
        }
        #pragma unroll
        for (int n = 2; n < 17; n += 4) {       // k=2: P only
            float c = tw[2 * n], s = tw[2 * n + 1];
            P2a = fmaf(tr0[n], c, fmaf(-ti0[n], s, P2a));
            P2b = fmaf(tr1[n], c, fmaf(-ti1[n], s, P2b));
        }
        #pragma unroll
        for (int n = 1; n < 17; n += 4) {       // k=1: P and Q
            float c = tw[2 * n], s = tw[2 * n + 1];
            P1a = fmaf(tr0[n], c, fmaf(-ti0[n], s, P1a));
            Q1a = fmaf(tr0[n], s, fmaf(ti0[n], c, Q1a));
            P1b = fmaf(tr1[n], c, fmaf(-ti1[n], s, P1b));
            Q1b = fmaf(tr1[n], s, fmaf(ti1[n], c, Q1b));
        }
        #pragma unroll
        for (int n = 3; n < 17; n += 4) {       // k=3: P and Q
            float c = tw[2 * n], s = tw[2 * n + 1];
            P3a = fmaf(tr0[n], c, fmaf(-ti0[n], s, P3a));
            Q3a = fmaf(tr0[n], s, fmaf(ti0[n], c, Q3a));
            P3b = fmaf(tr1[n], c, fmaf(-ti1[n], s, P3b));
            Q3b = fmaf(tr1[n], s, fmaf(ti1[n], c, Q3b));
        }
        // y(w'+64j) = Re(sum_k i^{jk} A_k)
        {
            float s02 = P0a + P2a, d02 = P0a - P2a;
            float s13 = P1a + P3a, dq = Q3a - Q1a;
            yb0[(size_t)wp * 64]         = s02 + s13;
            yb0[(size_t)(wp + 64) * 64]  = d02 + dq;
            yb0[(size_t)(wp + 128) * 64] = s02 - s13;
            yb0[(size_t)(wp + 192) * 64] = d02 - dq;
        }
        {
            float s02 = P0b + P2b, d02 = P0b - P2b;
            float s13 = P1b + P3b, dq = Q3b - Q1b;
            yb1[(size_t)wp * 64]         = s02 + s13;
            yb1[(size_t)(wp + 64) * 64]  = d02 + dq;
            yb1[(size_t)(wp + 128) * 64] = s02 - s13;
            yb1[(size_t)(wp + 192) * 64] = d02 - dq;
        }
    }
}

extern "C" void kernel_launch(void* const* d_in, const int* in_sizes, int n_in,
                              void* d_out, int out_size, void* d_ws, size_t ws_size,
                              hipStream_t stream) {
    (void)in_sizes; (void)n_in; (void)out_size; (void)ws_size;
    const float* x  = (const float*)d_in[0];
    const float* Wr = (const float*)d_in[1];
    const float* Wi = (const float*)d_in[2];
    float* out = (float*)d_out;
    float* ws  = (float*)d_ws;

    float* twD = ws;                 // 2304 floats ([64][36] padded)
    float* twB = ws + 2304;          // 16384 floats
    float* twC = ws + 18688;         // 32 floats
    float* G   = ws + 18720;         // 4456448 floats
    float* T   = G + 4456448;        // 4456448 floats
    float* P   = T;                  // alias: partials live in T's slot
    float* Z   = G;                  // alias: Z lives in dead G's slot

    k0_tw<<<32, 256, 0, stream>>>(twD, twB, twC);
    k1_fwdW<<<NB * NH / 2, 256, 0, stream>>>(x, twD, twC, G);
    k2a_hdft<<<dim3(NB * NM2, HQ), 256, 0, stream>>>(G, twB, P);
    k2b_mix<<<NM1 * NM2, 512, 0, stream>>>(P, Wr, Wi, Z);
    k2c_ihdft<<<dim3(NB * NM2, 8), 256, 0, stream>>>(Z, twB, T);
    k3_invW<<<NB * NH / 2, 256, 0, stream>>>(T, twD, out);
}